// Round 12
// baseline (58.821 us; speedup 1.0000x reference)
//
#include <hip/hip_runtime.h>

// Problem constants
#define NQ 20
#define DIMQ (1 << NQ)          // 2^20
#define NB 16                   // BATCH
#define NT 4                    // N_TERMS
#define RBITS 15                // low bits untouched by gates
#define NCOL (1 << (RBITS + 4)) // 2^15 r-values * 16 batches = 524288 columns

// U table layout in ws/LDS: per (k,b): 36 floats (16 complex interleaved + 4 pad)
//   base = (k*16 + b) * 36 ; entry (i,j): re at base + (i*4+j)*2, im at +1
//   stride 144 B -> b and b+8 share banks (2-way, free per m136).
#define USTRIDE 36
#define UTOT (64 * USTRIDE)     // 2304 floats = 9216 B

// In-quad lane exchanges as DPP quad_perm: pure VALU, 2 cyc, no ds-pipe.
//   sel [1,0,3,2] -> 0xB1 (lane^1), [2,3,0,1] -> 0x4E (lane^2),
//   [3,2,1,0] -> 0x1B (lane^3).
__device__ __forceinline__ float dpp_swap1(float x) {
  int r = __builtin_amdgcn_mov_dpp(__builtin_bit_cast(int, x), 0xB1, 0xF, 0xF, true);
  return __builtin_bit_cast(float, r);
}
__device__ __forceinline__ float dpp_swap2(float x) {
  int r = __builtin_amdgcn_mov_dpp(__builtin_bit_cast(int, x), 0x4E, 0xF, 0xF, true);
  return __builtin_bit_cast(float, r);
}
__device__ __forceinline__ float dpp_swap3(float x) {
  int r = __builtin_amdgcn_mov_dpp(__builtin_bit_cast(int, x), 0x1B, 0xF, 0xF, true);
  return __builtin_bit_cast(float, r);
}

// ---------------------------------------------------------------------------
// Kernel A: U[k,b] = exp(-i * H_k * t_{k,b}),  H_k = 0.5*(A + A^H), A = Hr + i Hi
// 256 threads: 64 tasks (k,b) x 4 rows. Scaling (2^-4) + 8-term Taylor +
// 4 squarings (trunc error ~1e-10, invisible at fp32 / 2.1e-4 threshold).
// ---------------------------------------------------------------------------
__global__ __launch_bounds__(256) void compute_u_kernel(
    const float* __restrict__ Hre, const float* __restrict__ Him,
    const float* __restrict__ tevo, float* __restrict__ uout) {
  __shared__ float er_s[64][4][4];
  __shared__ float ei_s[64][4][4];

  const int tid  = threadIdx.x;   // 0..255
  const int task = tid >> 2;      // 0..63
  const int row  = tid & 3;       // 0..3
  const int k    = task >> 4;     // 0..3
  const int b    = task & 15;     // 0..15

  float Ar[4][4], Ai[4][4];
#pragma unroll
  for (int i = 0; i < 4; i++) {
#pragma unroll
    for (int j = 0; j < 4; j++) {
      Ar[i][j] = Hre[k * 16 + i * 4 + j];
      Ai[i][j] = Him[k * 16 + i * 4 + j];
    }
  }
  const float t = tevo[k * NB + b];
  const float ts = t * (1.0f / 16.0f);  // scale 2^-4 folded in

  // G = -i * H * ts ; H = 0.5*(A + A^H)
  float Gr[4][4], Gi[4][4];
#pragma unroll
  for (int i = 0; i < 4; i++) {
#pragma unroll
    for (int j = 0; j < 4; j++) {
      const float hr = 0.5f * (Ar[i][j] + Ar[j][i]);
      const float hi = 0.5f * (Ai[i][j] - Ai[j][i]);
      Gr[i][j] = ts * hi;
      Gi[i][j] = -ts * hr;
    }
  }

  // Taylor: E = I + sum_{m=1..8} G^m/m!   (row `row` only; full G in regs)
  float Er[4], Ei[4], Tr[4], Ti[4];
#pragma unroll
  for (int j = 0; j < 4; j++) {
    Er[j] = (j == row) ? 1.0f : 0.0f;
    Ei[j] = 0.0f;
    Tr[j] = Er[j];
    Ti[j] = 0.0f;
  }
#pragma unroll
  for (int m = 1; m <= 8; m++) {
    const float inv = 1.0f / (float)m;
    float nr[4], ni[4];
#pragma unroll
    for (int j = 0; j < 4; j++) {
      float ar = 0.0f, ai = 0.0f;
#pragma unroll
      for (int p = 0; p < 4; p++) {
        ar += Tr[p] * Gr[p][j] - Ti[p] * Gi[p][j];
        ai += Tr[p] * Gi[p][j] + Ti[p] * Gr[p][j];
      }
      nr[j] = ar * inv;
      ni[j] = ai * inv;
    }
#pragma unroll
    for (int j = 0; j < 4; j++) {
      Tr[j] = nr[j]; Ti[j] = ni[j];
      Er[j] += nr[j]; Ei[j] += ni[j];
    }
  }

  // 4 squarings via LDS (uniform trip count -> barriers are safe)
  for (int q = 0; q < 4; q++) {
    __syncthreads();
#pragma unroll
    for (int j = 0; j < 4; j++) {
      er_s[task][row][j] = Er[j];
      ei_s[task][row][j] = Ei[j];
    }
    __syncthreads();
    float nr[4], ni[4];
#pragma unroll
    for (int j = 0; j < 4; j++) {
      float ar = 0.0f, ai = 0.0f;
#pragma unroll
      for (int p = 0; p < 4; p++) {
        ar += Er[p] * er_s[task][p][j] - Ei[p] * ei_s[task][p][j];
        ai += Er[p] * ei_s[task][p][j] + Ei[p] * er_s[task][p][j];
      }
      nr[j] = ar; ni[j] = ai;
    }
#pragma unroll
    for (int j = 0; j < 4; j++) { Er[j] = nr[j]; Ei[j] = ni[j]; }
  }

  // Store U rows: layout [k][b][16 complex interleaved], row stride 36 floats
  const int ubase = (k * 16 + b) * USTRIDE;
#pragma unroll
  for (int j = 0; j < 4; j++) {
    uout[ubase + (row * 4 + j) * 2]     = Er[j];
    uout[ubase + (row * 4 + j) * 2 + 1] = Ei[j];
  }
}

// ---------------------------------------------------------------------------
// Kernel B (r7 partition + all-DPP + LDS-staged U):
// FOUR lanes per column (one quad); lane owns quarter q = tid&3 of the 32-g
// group (8 amplitudes g = q*8 + m). col = blockIdx*64 + (tid>>2).
//   k=3 (g bits [1:0]), k=2 (bits [2:1]): pure in-thread.
//   k=1 (bits [3:2]): bit3 = q&1 -> partner lane^1 via DPP 0xB1.
//   k=0 (bits [4:3] = q): rotations d=1..3 via DPP 0xB1/0x4E/0x1B; d=1
//        reuses k1's swapped registers. U0 entry [q][q^d] loaded per-lane
//        as float2 (runtime-q ADDRESS arithmetic, never register indexing).
// Live set ~50 floats -> genuinely fits the allocator's ~64-VGPR comfort
// zone: loads stay burst-resident, no fold/remat churn, no spill, and
// 8 waves/SIMD occupancy. All exchanges are 2-cyc VALU (no ds_bpermute,
// which killed r7). U table staged to LDS (r8: global-U gather hurts).
// ---------------------------------------------------------------------------
__global__ __launch_bounds__(256, 4) void apply_gates_kernel(
    const float* __restrict__ sre, const float* __restrict__ sim,
    const float* __restrict__ u, float* __restrict__ out) {
  __shared__ __align__(16) float ul[UTOT];
  const int tid = threadIdx.x;
  const int q   = tid & 3;                       // owned quadrant = g bits [4:3]
  const int q0  = q & 1;                         // g bit 3
  const int col = blockIdx.x * 64 + (tid >> 2);  // r*16 + b
  const int b   = (tid >> 2) & 15;

  // own 8 amplitudes: g = q*8 + m  (one burst of 16 dword loads, issued first)
  float s_re[8], s_im[8];
#pragma unroll
  for (int m = 0; m < 8; m++) {
    const int off = col + ((q * 8 + m) << 19);
    s_re[m] = sre[off];
    s_im[m] = sim[off];
  }

  // stage U table (9 KiB) to LDS; UTOT = 9*256 exactly
#pragma unroll
  for (int qq = 0; qq < 9; qq++) ul[tid + qq * 256] = u[tid + qq * 256];
  __syncthreads();

  float o_re[8], o_im[8];

  // ---- k = 3 (g bits [1:0]) : in-thread; initializes acc ----
  // out[l2*4+i] = sum_j U3[i][j] * s[l2*4+j]
  {
    const float* ub = &ul[(3 * 16 + b) * USTRIDE];
#pragma unroll
    for (int i = 0; i < 4; i++) {
      const float4 v0 = *(const float4*)(ub + i * 8);      // entries j=0,1
      const float4 v1 = *(const float4*)(ub + i * 8 + 4);  // entries j=2,3
#pragma unroll
      for (int l2 = 0; l2 < 2; l2++) {
        const int o = l2 * 4 + i;
        const int a = l2 * 4;
        o_re[o] = v0.x * s_re[a]     - v0.y * s_im[a]
                + v0.z * s_re[a + 1] - v0.w * s_im[a + 1]
                + v1.x * s_re[a + 2] - v1.y * s_im[a + 2]
                + v1.z * s_re[a + 3] - v1.w * s_im[a + 3];
        o_im[o] = v0.x * s_im[a]     + v0.y * s_re[a]
                + v0.z * s_im[a + 1] + v0.w * s_re[a + 1]
                + v1.x * s_im[a + 2] + v1.y * s_re[a + 2]
                + v1.z * s_im[a + 3] + v1.w * s_re[a + 3];
      }
    }
  }

  // ---- k = 2 (g bits [2:1]) : in-thread ----
  // out[i*2+l0] += sum_j U2[i][j] * s[j*2+l0]
  {
    const float* ub = &ul[(2 * 16 + b) * USTRIDE];
#pragma unroll
    for (int i = 0; i < 4; i++) {
      const float4 v0 = *(const float4*)(ub + i * 8);
      const float4 v1 = *(const float4*)(ub + i * 8 + 4);
#pragma unroll
      for (int l0 = 0; l0 < 2; l0++) {
        const int o = i * 2 + l0;
        o_re[o] += v0.x * s_re[l0]     - v0.y * s_im[l0]
                 + v0.z * s_re[2 + l0] - v0.w * s_im[2 + l0]
                 + v1.x * s_re[4 + l0] - v1.y * s_im[4 + l0]
                 + v1.z * s_re[6 + l0] - v1.w * s_im[6 + l0];
        o_im[o] += v0.x * s_im[l0]     + v0.y * s_re[l0]
                 + v0.z * s_im[2 + l0] + v0.w * s_re[2 + l0]
                 + v1.x * s_im[4 + l0] + v1.y * s_re[4 + l0]
                 + v1.z * s_im[6 + l0] + v1.w * s_re[6 + l0];
      }
    }
  }

  // ---- k = 1 (g bits [3:2]) : partner = lane^1 (flips q0 = g bit 3) ----
  // t = partner's 8 complex via DPP; kept live through k0's d=1 rotation.
  float t_re[8], t_im[8];
#pragma unroll
  for (int m = 0; m < 8; m++) {
    t_re[m] = dpp_swap1(s_re[m]);
    t_im[m] = dpp_swap1(s_im[m]);
  }
  {
    const float* ub = &ul[(1 * 16 + b) * USTRIDE];
#pragma unroll
    for (int l2 = 0; l2 < 2; l2++) {
      const float* row = ub + (q0 * 2 + l2) * 8;
      const float2 co0 = *(const float2*)(row + (q0 * 2 + 0) * 2);        // own j2=0
      const float2 co1 = *(const float2*)(row + (q0 * 2 + 1) * 2);        // own j2=1
      const float2 cp0 = *(const float2*)(row + ((q0 ^ 1) * 2 + 0) * 2);  // partner j2=0
      const float2 cp1 = *(const float2*)(row + ((q0 ^ 1) * 2 + 1) * 2);  // partner j2=1
#pragma unroll
      for (int ll = 0; ll < 4; ll++) {
        const int o = l2 * 4 + ll;
        o_re[o] += co0.x * s_re[ll]     - co0.y * s_im[ll]
                 + co1.x * s_re[4 + ll] - co1.y * s_im[4 + ll]
                 + cp0.x * t_re[ll]     - cp0.y * t_im[ll]
                 + cp1.x * t_re[4 + ll] - cp1.y * t_im[4 + ll];
        o_im[o] += co0.x * s_im[ll]     + co0.y * s_re[ll]
                 + co1.x * s_im[4 + ll] + co1.y * s_re[4 + ll]
                 + cp0.x * t_im[ll]     + cp0.y * t_re[ll]
                 + cp1.x * t_im[4 + ll] + cp1.y * t_re[4 + ll];
      }
    }
  }

  // ---- k = 0 (g bits [4:3] = q) : rotations over d, U0 entry [q][q^d] ----
  {
    const float* ub = &ul[(0 * 16 + b) * USTRIDE];
    const float2 c0 = *(const float2*)(ub + q * 8 + q * 2);        // d=0: own
#pragma unroll
    for (int m = 0; m < 8; m++) {
      o_re[m] += c0.x * s_re[m] - c0.y * s_im[m];
      o_im[m] += c0.x * s_im[m] + c0.y * s_re[m];
    }
    // d = 1: reuse k1's swapped registers (t = lane^1 sources)
    const float2 c1 = *(const float2*)(ub + q * 8 + (q ^ 1) * 2);
#pragma unroll
    for (int m = 0; m < 8; m++) {
      o_re[m] += c1.x * t_re[m] - c1.y * t_im[m];
      o_im[m] += c1.x * t_im[m] + c1.y * t_re[m];
    }
    // d = 2: immediate-consume DPP (2 transient floats only)
    const float2 c2 = *(const float2*)(ub + q * 8 + (q ^ 2) * 2);
#pragma unroll
    for (int m = 0; m < 8; m++) {
      const float tr = dpp_swap2(s_re[m]);
      const float ti = dpp_swap2(s_im[m]);
      o_re[m] += c2.x * tr - c2.y * ti;
      o_im[m] += c2.x * ti + c2.y * tr;
    }
    // d = 3
    const float2 c3 = *(const float2*)(ub + q * 8 + (q ^ 3) * 2);
#pragma unroll
    for (int m = 0; m < 8; m++) {
      const float tr = dpp_swap3(s_re[m]);
      const float ti = dpp_swap3(s_im[m]);
      o_re[m] += c3.x * tr - c3.y * ti;
      o_im[m] += c3.x * ti + c3.y * tr;
    }
  }

#pragma unroll
  for (int m = 0; m < 8; m++) {
    const int off = col + ((q * 8 + m) << 19);
    __builtin_nontemporal_store(o_re[m], out + off);               // real
    __builtin_nontemporal_store(o_im[m], out + off + (1 << 24));   // imag
  }
}

extern "C" void kernel_launch(void* const* d_in, const int* in_sizes, int n_in,
                              void* d_out, int out_size, void* d_ws, size_t ws_size,
                              hipStream_t stream) {
  const float* Hre  = (const float*)d_in[0];
  const float* Him  = (const float*)d_in[1];
  const float* tevo = (const float*)d_in[2];
  const float* sre  = (const float*)d_in[3];
  const float* sim  = (const float*)d_in[4];
  float* out = (float*)d_out;
  float* uws = (float*)d_ws;  // UTOT floats = 9216 B

  compute_u_kernel<<<1, 256, 0, stream>>>(Hre, Him, tevo, uws);
  apply_gates_kernel<<<NCOL / 64, 256, 0, stream>>>(sre, sim, uws, out);
}

// Round 13
// 53.195 us; speedup vs baseline: 1.1057x; 1.1057x over previous
//
#include <hip/hip_runtime.h>

// Problem constants
#define NQ 20
#define DIMQ (1 << NQ)          // 2^20
#define NB 16                   // BATCH
#define NT 4                    // N_TERMS
#define RBITS 15                // low bits untouched by gates
#define NCOL (1 << (RBITS + 4)) // 2^15 r-values * 16 batches = 524288 columns

// U table layout in ws/LDS: per (k,b): 36 floats (16 complex interleaved + 4 pad)
//   base = (k*16 + b) * 36 ; entry (i,j): re at base + (i*4+j)*2, im at +1
//   36 floats = 144 B = 9*16 B -> every (k,b) base is 16B-aligned.
#define USTRIDE 36
#define UTOT (64 * USTRIDE)     // 2304 floats = 9216 B (= 576 float4 = 64 lanes x 9)

// lane <-> lane^1 exchange as DPP quad_perm [1,0,3,2] (0xB1): pure VALU,
// no lgkmcnt wait, no ds-pipe traffic (vs __shfl_xor = ds_bpermute).
__device__ __forceinline__ float dpp_swap1(float x) {
  int r = __builtin_amdgcn_mov_dpp(__builtin_bit_cast(int, x), 0xB1, 0xF, 0xF, true);
  return __builtin_bit_cast(float, r);
}

// ---------------------------------------------------------------------------
// Kernel A: U[k,b] = exp(-i * H_k * t_{k,b}),  H_k = 0.5*(A + A^H), A = Hr + i Hi
// 256 threads: 64 tasks (k,b) x 4 rows. Scaling (2^-4) + 8-term Taylor +
// 4 squarings (trunc error ~1e-10, invisible at fp32 / 2.1e-4 threshold).
// ---------------------------------------------------------------------------
__global__ __launch_bounds__(256) void compute_u_kernel(
    const float* __restrict__ Hre, const float* __restrict__ Him,
    const float* __restrict__ tevo, float* __restrict__ uout) {
  __shared__ float er_s[64][4][4];
  __shared__ float ei_s[64][4][4];

  const int tid  = threadIdx.x;   // 0..255
  const int task = tid >> 2;      // 0..63
  const int row  = tid & 3;       // 0..3
  const int k    = task >> 4;     // 0..3
  const int b    = task & 15;     // 0..15

  float Ar[4][4], Ai[4][4];
#pragma unroll
  for (int i = 0; i < 4; i++) {
#pragma unroll
    for (int j = 0; j < 4; j++) {
      Ar[i][j] = Hre[k * 16 + i * 4 + j];
      Ai[i][j] = Him[k * 16 + i * 4 + j];
    }
  }
  const float t = tevo[k * NB + b];
  const float ts = t * (1.0f / 16.0f);  // scale 2^-4 folded in

  // G = -i * H * ts ; H = 0.5*(A + A^H)
  float Gr[4][4], Gi[4][4];
#pragma unroll
  for (int i = 0; i < 4; i++) {
#pragma unroll
    for (int j = 0; j < 4; j++) {
      const float hr = 0.5f * (Ar[i][j] + Ar[j][i]);
      const float hi = 0.5f * (Ai[i][j] - Ai[j][i]);
      Gr[i][j] = ts * hi;
      Gi[i][j] = -ts * hr;
    }
  }

  // Taylor: E = I + sum_{m=1..8} G^m/m!   (row `row` only; full G in regs)
  float Er[4], Ei[4], Tr[4], Ti[4];
#pragma unroll
  for (int j = 0; j < 4; j++) {
    Er[j] = (j == row) ? 1.0f : 0.0f;
    Ei[j] = 0.0f;
    Tr[j] = Er[j];
    Ti[j] = 0.0f;
  }
#pragma unroll
  for (int m = 1; m <= 8; m++) {
    const float inv = 1.0f / (float)m;
    float nr[4], ni[4];
#pragma unroll
    for (int j = 0; j < 4; j++) {
      float ar = 0.0f, ai = 0.0f;
#pragma unroll
      for (int p = 0; p < 4; p++) {
        ar += Tr[p] * Gr[p][j] - Ti[p] * Gi[p][j];
        ai += Tr[p] * Gi[p][j] + Ti[p] * Gr[p][j];
      }
      nr[j] = ar * inv;
      ni[j] = ai * inv;
    }
#pragma unroll
    for (int j = 0; j < 4; j++) {
      Tr[j] = nr[j]; Ti[j] = ni[j];
      Er[j] += nr[j]; Ei[j] += ni[j];
    }
  }

  // 4 squarings via LDS (uniform trip count -> barriers are safe)
  for (int q = 0; q < 4; q++) {
    __syncthreads();
#pragma unroll
    for (int j = 0; j < 4; j++) {
      er_s[task][row][j] = Er[j];
      ei_s[task][row][j] = Ei[j];
    }
    __syncthreads();
    float nr[4], ni[4];
#pragma unroll
    for (int j = 0; j < 4; j++) {
      float ar = 0.0f, ai = 0.0f;
#pragma unroll
      for (int p = 0; p < 4; p++) {
        ar += Er[p] * er_s[task][p][j] - Ei[p] * ei_s[task][p][j];
        ai += Er[p] * ei_s[task][p][j] + Ei[p] * er_s[task][p][j];
      }
      nr[j] = ar; ni[j] = ai;
    }
#pragma unroll
    for (int j = 0; j < 4; j++) { Er[j] = nr[j]; Ei[j] = ni[j]; }
  }

  // Store U rows: layout [k][b][16 complex interleaved], row stride 36 floats
  const int ubase = (k * 16 + b) * USTRIDE;
#pragma unroll
  for (int j = 0; j < 4; j++) {
    uout[ubase + (row * 4 + j) * 2]     = Er[j];
    uout[ubase + (row * 4 + j) * 2 + 1] = Ei[j];
  }
}

// ---------------------------------------------------------------------------
// Kernel B (r10 core, BARRIER-FREE via per-wave U staging):
// two ADJACENT LANES per column (r,b); each owns one 16-g half.
//   half = tid&1, col = blockIdx*128 + (tid>>1), b = (tid>>1)&15.
// Each WAVE copies the 9 KiB U table into its own LDS region (9 x float4
// load + 9 x ds_write_b128 per lane -- same instruction count as the old
// block-wide scalar staging) and reads only from it. No __syncthreads():
// intra-wave LDS write->read ordering is handled by the compiler's lgkmcnt
// tracking, so waves drift freely -- wave 0 computes while wave 1's state
// burst is still in flight, instead of all 4 waves phase-locking on the
// block's slowest U-stage + full vmcnt(0) drain.
// Gates k=1..3 are half-local; k=0 cross term exchanged via DPP quad_perm.
// ---------------------------------------------------------------------------
__global__ __launch_bounds__(256, 4) void apply_gates_kernel(
    const float* __restrict__ sre, const float* __restrict__ sim,
    const float* __restrict__ u, float* __restrict__ out) {
  __shared__ __align__(16) float ul[4 * UTOT];      // 36864 B: one region/wave
  const int tid   = threadIdx.x;
  const int half  = tid & 1;                        // lanes alternate halves
  const int col   = blockIdx.x * 128 + (tid >> 1);  // r*16 + b
  const int b     = (tid >> 1) & 15;
  const int gbase = half << 4;

  // (1) own half: 16 complex -- one burst of 32 dword loads, issued FIRST
  float s_re[16], s_im[16];
#pragma unroll
  for (int q = 0; q < 16; q++) {
    const int off = col + ((gbase + q) << 19);
    s_re[q] = sre[off];
    s_im[q] = sim[off];
  }

  // (2) per-wave U staging: lane l copies float4s l, l+64, ..., l+512
  const int w = tid >> 6;
  const int l = tid & 63;
  float* uw = ul + w * UTOT;
  {
    const float4* u4 = (const float4*)u;
    float4* ul4 = (float4*)uw;
#pragma unroll
    for (int t = 0; t < 9; t++) ul4[l + 64 * t] = u4[l + 64 * t];
  }
  // no barrier: this wave only reads the region it just wrote (lgkmcnt).

  float o_re[16], o_im[16];

  // ---- k = 0 (g bits [4:3]) : own term + DPP-exchanged cross term ----
  // own output g = half<<4 | b3<<3 | l : row i = 2*half + b3.
  // own sources s_re[l] (j=2*half), s_re[8+l] (j=2*half+1).
  // cross partial: contribution of MY sources (same j) to partner output
  // with row i' = 2*(half^1) + b3; partner adds the swapped value.
  {
    const float* ub0 = &uw[b * USTRIDE];  // k = 0 block
    const int h4 = half * 4;              // float offset of (j=2h) entry pair
#pragma unroll
    for (int b3 = 0; b3 < 2; b3++) {
      const float4 vo = *(const float4*)(ub0 + (half * 2 + b3) * 8 + h4);
      const float4 vc = *(const float4*)(ub0 + ((half ^ 1) * 2 + b3) * 8 + h4);
#pragma unroll
      for (int ll = 0; ll < 8; ll++) {
        const int gq = b3 * 8 + ll;
        o_re[gq] = vo.x * s_re[ll]     - vo.y * s_im[ll]
                 + vo.z * s_re[8 + ll] - vo.w * s_im[8 + ll];
        o_im[gq] = vo.x * s_im[ll]     + vo.y * s_re[ll]
                 + vo.z * s_im[8 + ll] + vo.w * s_re[8 + ll];
        float pr = vc.x * s_re[ll]     - vc.y * s_im[ll]
                 + vc.z * s_re[8 + ll] - vc.w * s_im[8 + ll];
        float pi = vc.x * s_im[ll]     + vc.y * s_re[ll]
                 + vc.z * s_im[8 + ll] + vc.w * s_re[8 + ll];
        o_re[gq] += dpp_swap1(pr);
        o_im[gq] += dpp_swap1(pi);
      }
    }
  }

  // ---- k = 1..3: fully local to the half (bits [3:0] of g) ----
#pragma unroll
  for (int k = 1; k < 4; k++) {
    const int sh = 3 - k;  // 2, 1, 0
    const float* ub = &uw[(k * 16 + b) * USTRIDE];
#pragma unroll
    for (int i = 0; i < 4; i++) {
      const float4 v0 = *(const float4*)(ub + i * 8);      // j=0,1
      const float4 v1 = *(const float4*)(ub + i * 8 + 4);  // j=2,3
#pragma unroll
      for (int qq = 0; qq < 4; qq++) {
        const int low  = qq & ((1 << sh) - 1);
        const int high = (qq >> sh) << (sh + 2);
        const int gb   = high | low;           // gq with pair bits cleared
        const int gq   = gb | (i << sh);
        const int s0 = gb;
        const int s1 = gb | (1 << sh);
        const int s2 = gb | (2 << sh);
        const int s3 = gb | (3 << sh);
        o_re[gq] += v0.x * s_re[s0] - v0.y * s_im[s0]
                  + v0.z * s_re[s1] - v0.w * s_im[s1]
                  + v1.x * s_re[s2] - v1.y * s_im[s2]
                  + v1.z * s_re[s3] - v1.w * s_im[s3];
        o_im[gq] += v0.x * s_im[s0] + v0.y * s_re[s0]
                  + v0.z * s_im[s1] + v0.w * s_re[s1]
                  + v1.x * s_im[s2] + v1.y * s_re[s2]
                  + v1.z * s_im[s3] + v1.w * s_re[s3];
      }
    }
  }

#pragma unroll
  for (int q = 0; q < 16; q++) {
    const int off = col + ((gbase + q) << 19);
    __builtin_nontemporal_store(o_re[q], out + off);               // real
    __builtin_nontemporal_store(o_im[q], out + off + (1 << 24));   // imag
  }
}

extern "C" void kernel_launch(void* const* d_in, const int* in_sizes, int n_in,
                              void* d_out, int out_size, void* d_ws, size_t ws_size,
                              hipStream_t stream) {
  const float* Hre  = (const float*)d_in[0];
  const float* Him  = (const float*)d_in[1];
  const float* tevo = (const float*)d_in[2];
  const float* sre  = (const float*)d_in[3];
  const float* sim  = (const float*)d_in[4];
  float* out = (float*)d_out;
  float* uws = (float*)d_ws;  // UTOT floats = 9216 B

  compute_u_kernel<<<1, 256, 0, stream>>>(Hre, Him, tevo, uws);
  apply_gates_kernel<<<NCOL / 128, 256, 0, stream>>>(sre, sim, uws, out);
}

// Round 14
// 52.444 us; speedup vs baseline: 1.1216x; 1.0143x over previous
//
#include <hip/hip_runtime.h>

// Problem constants
#define NQ 20
#define DIMQ (1 << NQ)          // 2^20
#define NB 16                   // BATCH
#define NT 4                    // N_TERMS
#define RBITS 15                // low bits untouched by gates
#define NCOL (1 << (RBITS + 4)) // 2^15 r-values * 16 batches = 524288 columns

// U table layout in ws/LDS: per (k,b): 36 floats (16 complex interleaved + 4 pad)
//   base = (k*16 + b) * 36 ; entry (i,j): re at base + (i*4+j)*2, im at +1
//   36 floats = 144 B = 9*16 B -> every (k,b) base is 16B-aligned; 2-way banks.
#define USTRIDE 36
#define UTOT (64 * USTRIDE)     // 2304 floats = 9216 B (= 576 float4 = 64 lanes x 9)

// lane <-> lane^1 exchange as DPP quad_perm [1,0,3,2] (0xB1): pure VALU.
__device__ __forceinline__ float dpp_swap1(float x) {
  int r = __builtin_amdgcn_mov_dpp(__builtin_bit_cast(int, x), 0xB1, 0xF, 0xF, true);
  return __builtin_bit_cast(float, r);
}

// Complex MAC via packed-FP32 VOP3P: o += u * s  (u=(ur,ui), s=(sr,si)).
//   instr1: (o.x,o.y) += (ur*sr, ur*si)      [op_sel_hi src0=lo for hi lane]
//   instr2: (o.x,o.y) += (-ui*si, ui*sr)     [op_sel swaps, neg_lo on src0]
// 2 instructions per complex MAC vs 4 scalar FMAs.
__device__ __forceinline__ void cfma(float2& o, const float2 u, const float2 s) {
  asm("v_pk_fma_f32 %0, %1, %2, %0 op_sel_hi:[0,1,1]\n\t"
      "v_pk_fma_f32 %0, %1, %2, %0 op_sel:[1,1,0] op_sel_hi:[1,0,1] neg_lo:[1,0,0]"
      : "+v"(o) : "v"(u), "v"(s));
}
// o = u * s (no accumulate); early-clobber since %0 is written before last read.
__device__ __forceinline__ float2 cmul(const float2 u, const float2 s) {
  float2 o;
  asm("v_pk_mul_f32 %0, %1, %2 op_sel_hi:[0,1]\n\t"
      "v_pk_fma_f32 %0, %1, %2, %0 op_sel:[1,1,0] op_sel_hi:[1,0,1] neg_lo:[1,0,0]"
      : "=&v"(o) : "v"(u), "v"(s));
  return o;
}

// ---------------------------------------------------------------------------
// Kernel A: U[k,b] = exp(-i * H_k * t_{k,b}),  H_k = 0.5*(A + A^H), A = Hr + i Hi
// 256 threads: 64 tasks (k,b) x 4 rows. Scaling (2^-4) + 8-term Taylor +
// 4 squarings (trunc error ~1e-10, invisible at fp32 / 2.1e-4 threshold).
// ---------------------------------------------------------------------------
__global__ __launch_bounds__(256) void compute_u_kernel(
    const float* __restrict__ Hre, const float* __restrict__ Him,
    const float* __restrict__ tevo, float* __restrict__ uout) {
  __shared__ float er_s[64][4][4];
  __shared__ float ei_s[64][4][4];

  const int tid  = threadIdx.x;   // 0..255
  const int task = tid >> 2;      // 0..63
  const int row  = tid & 3;       // 0..3
  const int k    = task >> 4;     // 0..3
  const int b    = task & 15;     // 0..15

  float Ar[4][4], Ai[4][4];
#pragma unroll
  for (int i = 0; i < 4; i++) {
#pragma unroll
    for (int j = 0; j < 4; j++) {
      Ar[i][j] = Hre[k * 16 + i * 4 + j];
      Ai[i][j] = Him[k * 16 + i * 4 + j];
    }
  }
  const float t = tevo[k * NB + b];
  const float ts = t * (1.0f / 16.0f);  // scale 2^-4 folded in

  // G = -i * H * ts ; H = 0.5*(A + A^H)
  float Gr[4][4], Gi[4][4];
#pragma unroll
  for (int i = 0; i < 4; i++) {
#pragma unroll
    for (int j = 0; j < 4; j++) {
      const float hr = 0.5f * (Ar[i][j] + Ar[j][i]);
      const float hi = 0.5f * (Ai[i][j] - Ai[j][i]);
      Gr[i][j] = ts * hi;
      Gi[i][j] = -ts * hr;
    }
  }

  // Taylor: E = I + sum_{m=1..8} G^m/m!   (row `row` only; full G in regs)
  float Er[4], Ei[4], Tr[4], Ti[4];
#pragma unroll
  for (int j = 0; j < 4; j++) {
    Er[j] = (j == row) ? 1.0f : 0.0f;
    Ei[j] = 0.0f;
    Tr[j] = Er[j];
    Ti[j] = 0.0f;
  }
#pragma unroll
  for (int m = 1; m <= 8; m++) {
    const float inv = 1.0f / (float)m;
    float nr[4], ni[4];
#pragma unroll
    for (int j = 0; j < 4; j++) {
      float ar = 0.0f, ai = 0.0f;
#pragma unroll
      for (int p = 0; p < 4; p++) {
        ar += Tr[p] * Gr[p][j] - Ti[p] * Gi[p][j];
        ai += Tr[p] * Gi[p][j] + Ti[p] * Gr[p][j];
      }
      nr[j] = ar * inv;
      ni[j] = ai * inv;
    }
#pragma unroll
    for (int j = 0; j < 4; j++) {
      Tr[j] = nr[j]; Ti[j] = ni[j];
      Er[j] += nr[j]; Ei[j] += ni[j];
    }
  }

  // 4 squarings via LDS (uniform trip count -> barriers are safe)
  for (int q = 0; q < 4; q++) {
    __syncthreads();
#pragma unroll
    for (int j = 0; j < 4; j++) {
      er_s[task][row][j] = Er[j];
      ei_s[task][row][j] = Ei[j];
    }
    __syncthreads();
    float nr[4], ni[4];
#pragma unroll
    for (int j = 0; j < 4; j++) {
      float ar = 0.0f, ai = 0.0f;
#pragma unroll
      for (int p = 0; p < 4; p++) {
        ar += Er[p] * er_s[task][p][j] - Ei[p] * ei_s[task][p][j];
        ai += Er[p] * ei_s[task][p][j] + Ei[p] * er_s[task][p][j];
      }
      nr[j] = ar; ni[j] = ai;
    }
#pragma unroll
    for (int j = 0; j < 4; j++) { Er[j] = nr[j]; Ei[j] = ni[j]; }
  }

  // Store U rows: layout [k][b][16 complex interleaved], row stride 36 floats
  const int ubase = (k * 16 + b) * USTRIDE;
#pragma unroll
  for (int j = 0; j < 4; j++) {
    uout[ubase + (row * 4 + j) * 2]     = Er[j];
    uout[ubase + (row * 4 + j) * 2 + 1] = Ei[j];
  }
}

// ---------------------------------------------------------------------------
// Kernel B (r13 structure verbatim, scalar complex math -> packed VOP3P):
// two ADJACENT LANES per column (r,b); each owns one 16-g half.
// Per-wave U staging, no __syncthreads (waves drift freely). Gates k=1..3
// half-local; k=0 cross term via DPP quad_perm. All complex MACs are 2x
// v_pk_fma_f32 (halves the VALU stream vs 4 scalar FMAs).
// ---------------------------------------------------------------------------
__global__ __launch_bounds__(256, 4) void apply_gates_kernel(
    const float* __restrict__ sre, const float* __restrict__ sim,
    const float* __restrict__ u, float* __restrict__ out) {
  __shared__ __align__(16) float ul[4 * UTOT];      // 36864 B: one region/wave
  const int tid   = threadIdx.x;
  const int half  = tid & 1;                        // lanes alternate halves
  const int col   = blockIdx.x * 128 + (tid >> 1);  // r*16 + b
  const int b     = (tid >> 1) & 15;
  const int gbase = half << 4;

  // (1) own half: 16 complex -- one burst of 32 dword loads, issued FIRST
  float2 s[16];
#pragma unroll
  for (int q = 0; q < 16; q++) {
    const int off = col + ((gbase + q) << 19);
    s[q].x = sre[off];
    s[q].y = sim[off];
  }

  // (2) per-wave U staging: lane l copies float4s l, l+64, ..., l+512
  const int w = tid >> 6;
  const int l = tid & 63;
  float* uw = ul + w * UTOT;
  {
    const float4* u4 = (const float4*)u;
    float4* ul4 = (float4*)uw;
#pragma unroll
    for (int t = 0; t < 9; t++) ul4[l + 64 * t] = u4[l + 64 * t];
  }
  // no barrier: this wave only reads the region it just wrote (lgkmcnt).

  float2 o[16];

  // ---- k = 0 (g bits [4:3]) : own term + DPP-exchanged cross term ----
  // own output g = half<<4 | b3<<3 | l : row i = 2*half + b3.
  // own sources s[l] (j=2*half), s[8+l] (j=2*half+1).
  // cross partial: my sources' contribution to partner output with row
  // i' = 2*(half^1) + b3; partner adds the DPP-swapped value.
  {
    const float* ub0 = &uw[b * USTRIDE];  // k = 0 block
    const int h4 = half * 4;              // float offset of (j=2h) entry pair
#pragma unroll
    for (int b3 = 0; b3 < 2; b3++) {
      const float4 vo = *(const float4*)(ub0 + (half * 2 + b3) * 8 + h4);
      const float4 vc = *(const float4*)(ub0 + ((half ^ 1) * 2 + b3) * 8 + h4);
      const float2 vo0 = make_float2(vo.x, vo.y), vo1 = make_float2(vo.z, vo.w);
      const float2 vc0 = make_float2(vc.x, vc.y), vc1 = make_float2(vc.z, vc.w);
#pragma unroll
      for (int ll = 0; ll < 8; ll++) {
        const int gq = b3 * 8 + ll;
        o[gq] = cmul(vo0, s[ll]);
        cfma(o[gq], vo1, s[8 + ll]);
        float2 p = cmul(vc0, s[ll]);
        cfma(p, vc1, s[8 + ll]);
        o[gq].x += dpp_swap1(p.x);
        o[gq].y += dpp_swap1(p.y);
      }
    }
  }

  // ---- k = 1..3: fully local to the half (bits [3:0] of g) ----
#pragma unroll
  for (int k = 1; k < 4; k++) {
    const int sh = 3 - k;  // 2, 1, 0
    const float* ub = &uw[(k * 16 + b) * USTRIDE];
#pragma unroll
    for (int i = 0; i < 4; i++) {
      const float4 v0 = *(const float4*)(ub + i * 8);      // j=0,1
      const float4 v1 = *(const float4*)(ub + i * 8 + 4);  // j=2,3
      const float2 u0 = make_float2(v0.x, v0.y), u1 = make_float2(v0.z, v0.w);
      const float2 u2 = make_float2(v1.x, v1.y), u3 = make_float2(v1.z, v1.w);
#pragma unroll
      for (int qq = 0; qq < 4; qq++) {
        const int low  = qq & ((1 << sh) - 1);
        const int high = (qq >> sh) << (sh + 2);
        const int gb   = high | low;           // gq with pair bits cleared
        const int gq   = gb | (i << sh);
        cfma(o[gq], u0, s[gb]);
        cfma(o[gq], u1, s[gb | (1 << sh)]);
        cfma(o[gq], u2, s[gb | (2 << sh)]);
        cfma(o[gq], u3, s[gb | (3 << sh)]);
      }
    }
  }

#pragma unroll
  for (int q = 0; q < 16; q++) {
    const int off = col + ((gbase + q) << 19);
    __builtin_nontemporal_store(o[q].x, out + off);               // real
    __builtin_nontemporal_store(o[q].y, out + off + (1 << 24));   // imag
  }
}

extern "C" void kernel_launch(void* const* d_in, const int* in_sizes, int n_in,
                              void* d_out, int out_size, void* d_ws, size_t ws_size,
                              hipStream_t stream) {
  const float* Hre  = (const float*)d_in[0];
  const float* Him  = (const float*)d_in[1];
  const float* tevo = (const float*)d_in[2];
  const float* sre  = (const float*)d_in[3];
  const float* sim  = (const float*)d_in[4];
  float* out = (float*)d_out;
  float* uws = (float*)d_ws;  // UTOT floats = 9216 B

  compute_u_kernel<<<1, 256, 0, stream>>>(Hre, Him, tevo, uws);
  apply_gates_kernel<<<NCOL / 128, 256, 0, stream>>>(sre, sim, uws, out);
}